// Round 7
// baseline (441.103 us; speedup 1.0000x reference)
//
#include <hip/hip_runtime.h>
#include <math.h>

#define NB 4
#define SEQ 4096
#define HID 2048
#define DH 256
#define DV 512
#define NQKV 1024               // DH + DH + DV packed
#define CHUNK 128
#define NCH 32                  // SEQ/CHUNK
#define MROWS (NB * SEQ)        // 16384
#define GAMMA 0.96875f
#define GAMMA_INV 1.0322580645161290f
// log2(0.96875)
#define LOG2_GAMMA (-0.045803689613124794f)
// log2(10000)
#define LOG2_10000 13.287712379549449f

typedef __attribute__((ext_vector_type(8))) short short8;
typedef __attribute__((ext_vector_type(4))) float floatx4;
typedef __attribute__((ext_vector_type(16))) float floatx16;

// ---------------------------------------------------------------------------
// helpers
// ---------------------------------------------------------------------------
__device__ __forceinline__ unsigned short bf16_rne(float v) {
    unsigned int u = __float_as_uint(v);
    u += 0x7fff + ((u >> 16) & 1);
    return (unsigned short)(u >> 16);
}
__device__ __forceinline__ float b2f(unsigned short h) {
    return __uint_as_float((unsigned int)h << 16);
}

// async global->LDS, 16 bytes per lane. LDS dest = wave-uniform base + lane*16.
__device__ __forceinline__ void gld16(const void* g, void* l) {
    __builtin_amdgcn_global_load_lds(
        reinterpret_cast<const __attribute__((address_space(1))) unsigned int*>(
            reinterpret_cast<uintptr_t>(g)),
        reinterpret_cast<__attribute__((address_space(3))) unsigned int*>(
            reinterpret_cast<uintptr_t>(l)),
        16, 0, 0);
}

// ---------------------------------------------------------------------------
// Kernel 0a: X fp32 -> bf16 row-major [M][K].
// ---------------------------------------------------------------------------
__global__ __launch_bounds__(256) void xcvt_kernel(
    const float* __restrict__ X, unsigned short* __restrict__ Xb)
{
    const int i = blockIdx.x * 256 + threadIdx.x;   // one float4 per thread
    float4 x = ((const float4*)X)[i];
    ushort4 h;
    h.x = bf16_rne(x.x); h.y = bf16_rne(x.y);
    h.z = bf16_rne(x.z); h.w = bf16_rne(x.w);
    ((ushort4*)Xb)[i] = h;
}

// ---------------------------------------------------------------------------
// Kernel 0b: W_Q|W_K|W_V fp32 [K][Nregion] -> transposed packed bf16 Bt[n][k].
// ---------------------------------------------------------------------------
__global__ __launch_bounds__(256) void wcvt_kernel(
    const float* __restrict__ WQ, const float* __restrict__ WK,
    const float* __restrict__ WV, unsigned short* __restrict__ Bt)
{
    __shared__ unsigned short sh[64][65];
    const int bid = blockIdx.x;         // 32 k-tiles * 16 n-tiles
    const int kt = bid & 31;
    const int ntile = bid >> 5;
    const int k0 = kt * 64, n0 = ntile * 64;

    const float* W; int ld, nl0;
    if (n0 < 256)      { W = WQ; ld = DH; nl0 = n0; }
    else if (n0 < 512) { W = WK; ld = DH; nl0 = n0 - 256; }
    else               { W = WV; ld = DV; nl0 = n0 - 512; }

    const int t = threadIdx.x;
#pragma unroll
    for (int p = 0; p < 4; p++) {
        const int kl = (t >> 4) + p * 16;
        const int ng = (t & 15) * 4;
        float4 w = *(const float4*)&W[(size_t)(k0 + kl) * ld + nl0 + ng];
        sh[kl][ng + 0] = bf16_rne(w.x);
        sh[kl][ng + 1] = bf16_rne(w.y);
        sh[kl][ng + 2] = bf16_rne(w.z);
        sh[kl][ng + 3] = bf16_rne(w.w);
    }
    __syncthreads();
#pragma unroll
    for (int p = 0; p < 4; p++) {
        const int nl = (t >> 4) + p * 16;
        const int kg = (t & 15) * 4;
        ushort4 h;
        h.x = sh[kg + 0][nl]; h.y = sh[kg + 1][nl];
        h.z = sh[kg + 2][nl]; h.w = sh[kg + 3][nl];
        *(ushort4*)&Bt[(size_t)(n0 + nl) * HID + k0 + kg] = h;
    }
}

// ---------------------------------------------------------------------------
// Kernel 1: QKV projection, 32x32x16 bf16 MFMA + xPos epilogue.
// M=16384, N=1024, K=2048. Block tile 256x128, BK=64, 256 threads = 4 waves,
// wave tile 128x64 = 4x2 grid of 32x32 MFMAs (acc 128 fp32 regs).
// Rationale (round 7): LDS BW is the limiter; wave-tile 128x64 halves LDS
// fragment bytes per FLOP vs 64x32 -> predicted MfmaUtil ~45%.
// k-step loop is nounroll so only a[4]+b[2] frags (24 VGPRs) are live.
// Outputs (bf16): Qb[m][256], Kb[m][256], Kt[dh][m], Vt[dv][m].
// ---------------------------------------------------------------------------
__global__ __launch_bounds__(256, 1) void qkv_mfma_kernel(
    const unsigned short* __restrict__ Xb, const unsigned short* __restrict__ Bt,
    unsigned short* __restrict__ Qb, unsigned short* __restrict__ Kb,
    unsigned short* __restrict__ Kt, unsigned short* __restrict__ Vt)
{
    __shared__ unsigned short As[256 * 64];   // [row][64 k-elems], 32 KB
    __shared__ unsigned short Bs[128 * 64];   // [row][64 k-elems], 16 KB

    // XCD swizzle: 8 n-tiles of one m-tile share bid&7 -> same XCD L2.
    const int bid = blockIdx.x;          // 512 blocks
    const int xcd = bid & 7;
    const int nt  = (bid >> 3) & 7;      // 8 n-tiles (128 cols each)
    const int mt  = (xcd << 3) | (bid >> 6);   // 64 m-tiles (256 rows each)
    const int m0 = mt * 256, n0 = nt * 128;

    const int t = threadIdx.x;
    const int w = t >> 6, lane = t & 63;
    const int wm = (w & 1) << 7;         // 0,128
    const int wn = (w >> 1) << 6;        // 0,64

    floatx16 acc[4][2];
#pragma unroll
    for (int i = 0; i < 4; i++)
#pragma unroll
        for (int j = 0; j < 2; j++) acc[i][j] = (floatx16)0.0f;

    // staging: per gld16 call a wave covers 8 rows x 64 elems (8 KB/4 waves)
    const int srow = lane >> 3;          // 0..7
    const int scol = (lane & 7) * 8;     // k-elem offset
    // fragment addressing (32x32x16): A[m = lane&31][k = (lane>>5)*8 ..+8]
    const int fm = lane & 31;
    const int fk = (lane >> 5) * 8;

    for (int k0 = 0; k0 < HID; k0 += 64) {
        __syncthreads();
#pragma unroll
        for (int p = 0; p < 8; p++)
            gld16(&Xb[(size_t)(m0 + p * 32 + w * 8 + srow) * HID + k0 + scol],
                  &As[(p * 32 + w * 8) * 64]);
#pragma unroll
        for (int p = 0; p < 4; p++)
            gld16(&Bt[(size_t)(n0 + p * 32 + w * 8 + srow) * HID + k0 + scol],
                  &Bs[(p * 32 + w * 8) * 64]);
        __syncthreads();

#pragma nounroll
        for (int s = 0; s < 4; s++) {            // 4 k-steps of 16
            short8 a[4], bb[2];
#pragma unroll
            for (int i = 0; i < 4; i++)
                a[i] = *(const short8*)&As[(wm + 32 * i + fm) * 64 + s * 16 + fk];
#pragma unroll
            for (int j = 0; j < 2; j++)
                bb[j] = *(const short8*)&Bs[(wn + 32 * j + fm) * 64 + s * 16 + fk];
#pragma unroll
            for (int i = 0; i < 4; i++)
#pragma unroll
                for (int j = 0; j < 2; j++)
                    acc[i][j] = __builtin_amdgcn_mfma_f32_32x32x16_bf16(
                        a[i], bb[j], acc[i][j], 0, 0, 0);
        }
    }

    // epilogue. 32x32 C/D layout: col = lane&31, row = (r&3)+8*(r>>2)+4*(lane>>5)
    const int cl = lane & 31;
    const int rhi = (lane >> 5) * 4;
    if (n0 >= 512) {
#pragma unroll
        for (int i = 0; i < 4; i++)
#pragma unroll
            for (int j = 0; j < 2; j++) {
                const int c = n0 - 512 + wn + 32 * j + cl;   // dv 0..511
#pragma unroll
                for (int r = 0; r < 16; r++) {
                    const int m = m0 + wm + 32 * i + (r & 3) + 8 * (r >> 2) + rhi;
                    Vt[(size_t)c * MROWS + m] = bf16_rne(acc[i][j][r]);
                }
            }
    } else {
        const bool isQ = (n0 < 256);
        unsigned short* dst = isQ ? Qb : Kb;
        const float sgn = isQ ? 1.f : -1.f;     // K downscaled
        const int nb = isQ ? n0 : n0 - 256;
#pragma unroll
        for (int j = 0; j < 2; j++) {
            const int c = nb + wn + 32 * j + cl;
            const float jj = (float)(c >> 1);
            const float sv = (2.f * jj + 0.4f * 256.f) * (1.f / (1.4f * 256.f));
            const float l2sv = __log2f(sv) * sgn * (1.f / 512.f);
            const float invf = exp2f(jj * (-LOG2_10000 / 128.f));
            const bool odd = (c & 1) != 0;
#pragma unroll
            for (int i = 0; i < 4; i++) {
#pragma unroll
                for (int r = 0; r < 16; r++) {
                    const int m = m0 + wm + 32 * i + (r & 3) + 8 * (r >> 2) + rhi;
                    const float s = (float)(m & (SEQ - 1));
                    const float x = acc[i][j][r];
                    const float p = __shfl_xor(x, 1, 64);   // partner col c^1
                    const float sc = exp2f(s * l2sv);
                    const float ang = s * invf;
                    const float sn = __sinf(ang), cs = __cosf(ang);
                    const float o = odd ? sc * (x * cs + p * sn)
                                        : sc * (x * cs - p * sn);
                    const unsigned short hv = bf16_rne(o);
                    dst[(size_t)m * DH + c] = hv;
                    if (!isQ) Kt[(size_t)c * MROWS + m] = hv;
                }
            }
        }
    }
}

// ---------------------------------------------------------------------------
// Kernel 2: per-chunk U_c^T = V^T diag(gamma^(C-i)) K, via bf16 MFMA.
// C[m=dv][n=dh] = sum_i Vt[dv][i] * (gamma^(C-i) Kt[dh][i]).
// Output Ut[b][c][dv 512][dh 256] fp32. Block = 128(dv) x 128(dh), K=128,
// 512 threads / 8 waves, wave 64x32. Grid = 4*32*4*2 = 1024.
// ---------------------------------------------------------------------------
__global__ __launch_bounds__(512, 1) void chunk_kv_kernel(
    const unsigned short* __restrict__ Kt, const unsigned short* __restrict__ Vt,
    float* __restrict__ Ut)
{
    __shared__ unsigned short As[128 * 32];   // Vt rows (dv) x i
    __shared__ unsigned short Bs[128 * 32];   // scaled Kt rows (dh) x i

    const int bid = blockIdx.x;      // 1024
    const int dht = bid & 1;
    const int vq  = (bid >> 1) & 3;
    const int c   = (bid >> 3) & 31;
    const int b   = bid >> 8;
    const int dh0 = dht * 128, dv0 = vq * 128;
    const int row0 = b * SEQ + c * CHUNK;

    const int t = threadIdx.x;
    const int w = t >> 6, lane = t & 63;
    const int wm = (w & 1) << 6;         // dv offset
    const int wn = (w >> 1) << 5;        // dh offset
    const int srow = lane >> 2, scol = (lane & 3) * 8;
    const int fr = lane & 15, fq = (lane >> 4) * 8;

    floatx4 acc[4][2];
#pragma unroll
    for (int i = 0; i < 4; i++)
#pragma unroll
        for (int j = 0; j < 2; j++) acc[i][j] = (floatx4)0.0f;

    const int kr = t >> 2, kc = (t & 3) * 8;   // B staging: 128 rows x 32 cols

    for (int i0 = 0; i0 < CHUNK; i0 += 32) {
        __syncthreads();
        gld16(&Vt[(size_t)(dv0 + w * 16 + srow) * MROWS + row0 + i0 + scol],
              &As[(w * 16) * 32]);
        {
            const unsigned short* src = &Kt[(size_t)(dh0 + kr) * MROWS + row0 + i0 + kc];
            ushort4 k0v = *(const ushort4*)src;
            ushort4 k1v = *(const ushort4*)(src + 4);
            float g = exp2f((float)(CHUNK - i0 - kc) * LOG2_GAMMA);  // gamma^(C-i)
            ushort4 h0, h1;
            h0.x = bf16_rne(b2f(k0v.x) * g); g *= GAMMA_INV;
            h0.y = bf16_rne(b2f(k0v.y) * g); g *= GAMMA_INV;
            h0.z = bf16_rne(b2f(k0v.z) * g); g *= GAMMA_INV;
            h0.w = bf16_rne(b2f(k0v.w) * g); g *= GAMMA_INV;
            h1.x = bf16_rne(b2f(k1v.x) * g); g *= GAMMA_INV;
            h1.y = bf16_rne(b2f(k1v.y) * g); g *= GAMMA_INV;
            h1.z = bf16_rne(b2f(k1v.z) * g); g *= GAMMA_INV;
            h1.w = bf16_rne(b2f(k1v.w) * g);
            *(ushort4*)&Bs[kr * 32 + kc] = h0;
            *(ushort4*)&Bs[kr * 32 + kc + 4] = h1;
        }
        __syncthreads();
        short8 a[4], bb[2];
#pragma unroll
        for (int i = 0; i < 4; i++)
            a[i] = *(const short8*)&As[(wm + i * 16 + fr) * 32 + fq];
#pragma unroll
        for (int j = 0; j < 2; j++)
            bb[j] = *(const short8*)&Bs[(wn + j * 16 + fr) * 32 + fq];
#pragma unroll
        for (int i = 0; i < 4; i++)
#pragma unroll
            for (int j = 0; j < 2; j++)
                acc[i][j] = __builtin_amdgcn_mfma_f32_16x16x32_bf16(a[i], bb[j], acc[i][j], 0, 0, 0);
    }

    // store: C[m=dv][n=dh] -> Ut[((b*32+c)*512 + dv0+m)*256 + dh0+n]
    const int cl = lane & 15, rq = (lane >> 4) << 2;
    const size_t ubase = ((size_t)(b * NCH + c) * DV + dv0) * DH + dh0;
#pragma unroll
    for (int i = 0; i < 4; i++)
#pragma unroll
        for (int j = 0; j < 2; j++) {
            const int n = wn + j * 16 + cl;
#pragma unroll
            for (int r = 0; r < 4; r++) {
                const int m = wm + i * 16 + rq + r;
                Ut[ubase + (size_t)m * DH + n] = acc[i][j][r];
            }
        }
}

// ---------------------------------------------------------------------------
// Kernel 3: exclusive scan over chunks; emits bf16 state Sb[c] = S_c
// (state BEFORE chunk c), layout [b][c][dv][dh] (B-operand-ready).
// ---------------------------------------------------------------------------
__global__ __launch_bounds__(256) void scan_kernel(
    const float* __restrict__ Ut, unsigned short* __restrict__ Sb)
{
    const int t = blockIdx.x * 256 + threadIdx.x;   // 0..524287
    const int b = t >> 17;                          // DV*DH = 131072
    const int r = t & 131071;
    const float gC = exp2f((float)CHUNK * LOG2_GAMMA);
    float s = 0.f;
    const size_t base = (size_t)b * NCH * 131072 + r;
    for (int c = 0; c < NCH; c++) {
        const size_t off = base + (size_t)c * 131072;
        const float u = Ut[off];
        Sb[off] = bf16_rne(s);
        s = gC * s + u;
    }
}

// ---------------------------------------------------------------------------
// Kernel 4: O = (tril(QK^T) .* gamma^(i-j)) @ V  +  (gamma^i Q) @ S_c^T.
// Full bf16 MFMA, 512 threads = 8 waves, wave 64x32. BK=64 in phases 1/3.
// Block = (b, chunk, dv-quarter): 128(i) x 128(dv) output. Grid = 512.
// ---------------------------------------------------------------------------
__global__ __launch_bounds__(512, 1) void out_mfma_kernel(
    const unsigned short* __restrict__ Qb, const unsigned short* __restrict__ Kb,
    const unsigned short* __restrict__ Vt, const unsigned short* __restrict__ Sb,
    float* __restrict__ out)
{
    __shared__ unsigned short Pa[128 * 136];   // P bf16, row stride 136 (pad)
    __shared__ unsigned short As[2 * 128 * 32];
    __shared__ unsigned short Bs[2 * 128 * 32];

    const int bid = blockIdx.x;      // 512
    const int vq = bid & 3;
    const int c  = (bid >> 2) & 31;
    const int b  = bid >> 7;
    const int dv0 = vq * 128;
    const int row0 = b * SEQ + c * CHUNK;

    const int t = threadIdx.x;
    const int w = t >> 6, lane = t & 63;
    const int wm = (w & 1) << 6;         // 0,64
    const int wn = (w >> 1) << 5;        // 0,32,64,96
    const int fr = lane & 15, fq = (lane >> 4) * 8;
    const int cl = lane & 15, rq = (lane >> 4) << 2;
    const int srow = lane >> 2, scol = (lane & 3) * 8;

    floatx4 acc[4][2];
#pragma unroll
    for (int i = 0; i < 4; i++)
#pragma unroll
        for (int j = 0; j < 2; j++) acc[i][j] = (floatx4)0.0f;

    // ---------------- phase 1: P = Q K^T (BK=64) ----------------
    for (int d0 = 0; d0 < DH; d0 += 64) {
        __syncthreads();
        gld16(&Qb[(size_t)(row0 + w * 16 + srow) * DH + d0 + scol], &As[(w * 16) * 32]);
        gld16(&Qb[(size_t)(row0 + w * 16 + srow) * DH + d0 + 32 + scol], &As[4096 + (w * 16) * 32]);
        gld16(&Kb[(size_t)(row0 + w * 16 + srow) * DH + d0 + scol], &Bs[(w * 16) * 32]);
        gld16(&Kb[(size_t)(row0 + w * 16 + srow) * DH + d0 + 32 + scol], &Bs[4096 + (w * 16) * 32]);
        __syncthreads();
#pragma nounroll
        for (int s = 0; s < 2; s++) {
            short8 a[4], bb[2];
#pragma unroll
            for (int i = 0; i < 4; i++)
                a[i] = *(const short8*)&As[s * 4096 + (wm + i * 16 + fr) * 32 + fq];
#pragma unroll
            for (int j = 0; j < 2; j++)
                bb[j] = *(const short8*)&Bs[s * 4096 + (wn + j * 16 + fr) * 32 + fq];
#pragma unroll
            for (int i = 0; i < 4; i++)
#pragma unroll
                for (int j = 0; j < 2; j++)
                    acc[i][j] = __builtin_amdgcn_mfma_f32_16x16x32_bf16(a[i], bb[j], acc[i][j], 0, 0, 0);
        }
    }

    // decay mask + bf16 -> Pa[i][j] (i = q row in chunk, j = k row)
#pragma unroll
    for (int i = 0; i < 4; i++)
#pragma unroll
        for (int j = 0; j < 2; j++) {
            const int jj = wn + j * 16 + cl;
#pragma unroll
            for (int r = 0; r < 4; r++) {
                const int ii = wm + i * 16 + rq + r;
                const int diff = ii - jj;
                const float v = (diff >= 0) ? acc[i][j][r] * exp2f((float)diff * LOG2_GAMMA) : 0.f;
                Pa[ii * 136 + jj] = bf16_rne(v);
            }
            acc[i][j] = (floatx4)0.0f;     // reset for O accumulation
        }

    // ---------------- phase 2: acc = P @ V (BK=64, K=128 total) ----------
    for (int k0 = 0; k0 < CHUNK; k0 += 64) {
        __syncthreads();   // first iter: Pa visible; later: Bs reads done
        gld16(&Vt[(size_t)(dv0 + w * 16 + srow) * MROWS + row0 + k0 + scol], &Bs[(w * 16) * 32]);
        gld16(&Vt[(size_t)(dv0 + w * 16 + srow) * MROWS + row0 + k0 + 32 + scol], &Bs[4096 + (w * 16) * 32]);
        __syncthreads();
#pragma nounroll
        for (int s = 0; s < 2; s++) {
            short8 a[4], bb[2];
#pragma unroll
            for (int i = 0; i < 4; i++)
                a[i] = *(const short8*)&Pa[(wm + i * 16 + fr) * 136 + k0 + s * 32 + fq];
#pragma unroll
            for (int j = 0; j < 2; j++)
                bb[j] = *(const short8*)&Bs[s * 4096 + (wn + j * 16 + fr) * 32 + fq];
#pragma unroll
            for (int i = 0; i < 4; i++)
#pragma unroll
                for (int j = 0; j < 2; j++)
                    acc[i][j] = __builtin_amdgcn_mfma_f32_16x16x32_bf16(a[i], bb[j], acc[i][j], 0, 0, 0);
        }
    }

    // ---------------- phase 3: acc += (gamma^i Q) @ Sb (BK=64) ------------
    const size_t sbbase = ((size_t)(b * NCH + c) * DV + dv0) * DH;
    const int xr = t >> 2, xc = (t & 3) * 8;     // A staging: 128 rows x 32 cols
    const float gx = exp2f((float)xr * LOG2_GAMMA);   // gamma^i
    for (int d0 = 0; d0 < DH; d0 += 64) {
        __syncthreads();
#pragma unroll
        for (int s = 0; s < 2; s++) {
            const unsigned short* src = &Qb[(size_t)(row0 + xr) * DH + d0 + s * 32 + xc];
            ushort4 q0 = *(const ushort4*)src;
            ushort4 q1 = *(const ushort4*)(src + 4);
            ushort4 h0, h1;
            h0.x = bf16_rne(b2f(q0.x) * gx); h0.y = bf16_rne(b2f(q0.y) * gx);
            h0.z = bf16_rne(b2f(q0.z) * gx); h0.w = bf16_rne(b2f(q0.w) * gx);
            h1.x = bf16_rne(b2f(q1.x) * gx); h1.y = bf16_rne(b2f(q1.y) * gx);
            h1.z = bf16_rne(b2f(q1.z) * gx); h1.w = bf16_rne(b2f(q1.w) * gx);
            *(ushort4*)&As[s * 4096 + xr * 32 + xc] = h0;
            *(ushort4*)&As[s * 4096 + xr * 32 + xc + 4] = h1;
        }
        gld16(&Sb[sbbase + (size_t)(w * 16 + srow) * DH + d0 + scol], &Bs[(w * 16) * 32]);
        gld16(&Sb[sbbase + (size_t)(w * 16 + srow) * DH + d0 + 32 + scol], &Bs[4096 + (w * 16) * 32]);
        __syncthreads();
#pragma nounroll
        for (int s = 0; s < 2; s++) {
            short8 a[4], bb[2];
#pragma unroll
            for (int i = 0; i < 4; i++)
                a[i] = *(const short8*)&As[s * 4096 + (wm + i * 16 + fr) * 32 + fq];
#pragma unroll
            for (int j = 0; j < 2; j++)
                bb[j] = *(const short8*)&Bs[s * 4096 + (wn + j * 16 + fr) * 32 + fq];
#pragma unroll
            for (int i = 0; i < 4; i++)
#pragma unroll
                for (int j = 0; j < 2; j++)
                    acc[i][j] = __builtin_amdgcn_mfma_f32_16x16x32_bf16(a[i], bb[j], acc[i][j], 0, 0, 0);
        }
    }

    // epilogue: fp32 store
#pragma unroll
    for (int i = 0; i < 4; i++)
#pragma unroll
        for (int j = 0; j < 2; j++) {
            const int dv = dv0 + wn + j * 16 + cl;
#pragma unroll
            for (int r = 0; r < 4; r++) {
                const int m = row0 + wm + i * 16 + rq + r;
                out[(size_t)m * DV + dv] = acc[i][j][r];
            }
        }
}

// ---------------------------------------------------------------------------
extern "C" void kernel_launch(void* const* d_in, const int* in_sizes, int n_in,
                              void* d_out, int out_size, void* d_ws, size_t ws_size,
                              hipStream_t stream) {
    const float* X  = (const float*)d_in[0];
    const float* WQ = (const float*)d_in[1];
    const float* WK = (const float*)d_in[2];
    const float* WV = (const float*)d_in[3];
    float* out = (float*)d_out;

    // Workspace layout (bf16 unless noted):
    //   Qb 8.4 | Kb 8.4 | Kt 8.4 | Vt 16.8 | Sb 33.5 | Ut fp32 67.1 | Bt 4.2
    //   Xb (67.1) OVERLAPS Ut (Xb dead after qkv; Ut written after). ~147 MB.
    char* ws = (char*)d_ws;
    unsigned short* Qb = (unsigned short*)ws;
    unsigned short* Kb = Qb + (size_t)MROWS * DH;
    unsigned short* Kt = Kb + (size_t)MROWS * DH;
    unsigned short* Vt = Kt + (size_t)MROWS * DH;
    unsigned short* Sb = Vt + (size_t)MROWS * DV;
    float*          Ut = (float*)(Sb + (size_t)NB * NCH * DV * DH);
    unsigned short* Xb = (unsigned short*)Ut;       // overlap
    unsigned short* Bt = (unsigned short*)(Ut + (size_t)NB * NCH * DV * DH);

    xcvt_kernel<<<(MROWS * HID / 4) / 256, 256, 0, stream>>>(X, Xb);
    wcvt_kernel<<<512, 256, 0, stream>>>(WQ, WK, WV, Bt);
    qkv_mfma_kernel<<<512, 256, 0, stream>>>(Xb, Bt, Qb, Kb, Kt, Vt);
    chunk_kv_kernel<<<1024, 512, 0, stream>>>(Kt, Vt, Ut);
    scan_kernel<<<2048, 256, 0, stream>>>(Ut, Sb);
    out_mfma_kernel<<<512, 512, 0, stream>>>(Qb, Kb, Vt, Sb, out);
}

// Round 8
// 391.139 us; speedup vs baseline: 1.1277x; 1.1277x over previous
//
#include <hip/hip_runtime.h>
#include <math.h>

#define NB 4
#define SEQ 4096
#define HID 2048
#define DH 256
#define DV 512
#define NQKV 1024               // DH + DH + DV packed
#define CHUNK 128
#define NCH 32                  // SEQ/CHUNK
#define MROWS (NB * SEQ)        // 16384
#define GAMMA 0.96875f
#define GAMMA_INV 1.0322580645161290f
// log2(0.96875)
#define LOG2_GAMMA (-0.045803689613124794f)
// log2(10000)
#define LOG2_10000 13.287712379549449f

typedef __attribute__((ext_vector_type(8))) short short8;
typedef __attribute__((ext_vector_type(4))) float floatx4;
typedef __attribute__((ext_vector_type(16))) float floatx16;

// ---------------------------------------------------------------------------
// helpers
// ---------------------------------------------------------------------------
__device__ __forceinline__ unsigned short bf16_rne(float v) {
    unsigned int u = __float_as_uint(v);
    u += 0x7fff + ((u >> 16) & 1);
    return (unsigned short)(u >> 16);
}
__device__ __forceinline__ float b2f(unsigned short h) {
    return __uint_as_float((unsigned int)h << 16);
}

// async global->LDS, 16 bytes per lane. LDS dest = wave-uniform base + lane*16.
__device__ __forceinline__ void gld16(const void* g, void* l) {
    __builtin_amdgcn_global_load_lds(
        reinterpret_cast<const __attribute__((address_space(1))) unsigned int*>(
            reinterpret_cast<uintptr_t>(g)),
        reinterpret_cast<__attribute__((address_space(3))) unsigned int*>(
            reinterpret_cast<uintptr_t>(l)),
        16, 0, 0);
}

// ---------------------------------------------------------------------------
// Kernel 0a: X fp32 -> bf16 row-major [M][K].
// ---------------------------------------------------------------------------
__global__ __launch_bounds__(256) void xcvt_kernel(
    const float* __restrict__ X, unsigned short* __restrict__ Xb)
{
    const int i = blockIdx.x * 256 + threadIdx.x;   // one float4 per thread
    float4 x = ((const float4*)X)[i];
    ushort4 h;
    h.x = bf16_rne(x.x); h.y = bf16_rne(x.y);
    h.z = bf16_rne(x.z); h.w = bf16_rne(x.w);
    ((ushort4*)Xb)[i] = h;
}

// ---------------------------------------------------------------------------
// Kernel 0b: W_Q|W_K|W_V fp32 [K][Nregion] -> transposed packed bf16 Bt[n][k].
// ---------------------------------------------------------------------------
__global__ __launch_bounds__(256) void wcvt_kernel(
    const float* __restrict__ WQ, const float* __restrict__ WK,
    const float* __restrict__ WV, unsigned short* __restrict__ Bt)
{
    __shared__ unsigned short sh[64][65];
    const int bid = blockIdx.x;         // 32 k-tiles * 16 n-tiles
    const int kt = bid & 31;
    const int ntile = bid >> 5;
    const int k0 = kt * 64, n0 = ntile * 64;

    const float* W; int ld, nl0;
    if (n0 < 256)      { W = WQ; ld = DH; nl0 = n0; }
    else if (n0 < 512) { W = WK; ld = DH; nl0 = n0 - 256; }
    else               { W = WV; ld = DV; nl0 = n0 - 512; }

    const int t = threadIdx.x;
#pragma unroll
    for (int p = 0; p < 4; p++) {
        const int kl = (t >> 4) + p * 16;
        const int ng = (t & 15) * 4;
        float4 w = *(const float4*)&W[(size_t)(k0 + kl) * ld + nl0 + ng];
        sh[kl][ng + 0] = bf16_rne(w.x);
        sh[kl][ng + 1] = bf16_rne(w.y);
        sh[kl][ng + 2] = bf16_rne(w.z);
        sh[kl][ng + 3] = bf16_rne(w.w);
    }
    __syncthreads();
#pragma unroll
    for (int p = 0; p < 4; p++) {
        const int nl = (t >> 4) + p * 16;
        const int kg = (t & 15) * 4;
        ushort4 h;
        h.x = sh[kg + 0][nl]; h.y = sh[kg + 1][nl];
        h.z = sh[kg + 2][nl]; h.w = sh[kg + 3][nl];
        *(ushort4*)&Bt[(size_t)(n0 + nl) * HID + k0 + kg] = h;
    }
}

// ---------------------------------------------------------------------------
// Kernel 1: QKV projection, 32x32x16 bf16 MFMA + xPos epilogue.
// M=16384, N=1024, K=2048. Block tile 256x128, BK=64, 256 threads = 4 waves,
// wave tile 128x64 = 4x2 grid of 32x32 MFMAs (acc 128 fp32 regs).
//
// Round-8 fix: LDS rows are 128 B = 32 dwords, so un-swizzled fragment reads
// hit ONE bank group (round 7: 4.4e7 conflict-cycles = ~40% of kernel).
// XOR-swizzle 16B chunks within each row: slot = chunk ^ (row&7). The
// global_load_lds source address carries the swizzle (dest is lane-ordered);
// fragment reads invert it. Residual 4-way aliasing costs only 1.58x (m136).
// ---------------------------------------------------------------------------
__global__ __launch_bounds__(256, 2) void qkv_mfma_kernel(
    const unsigned short* __restrict__ Xb, const unsigned short* __restrict__ Bt,
    unsigned short* __restrict__ Qb, unsigned short* __restrict__ Kb,
    unsigned short* __restrict__ Kt, unsigned short* __restrict__ Vt)
{
    __shared__ unsigned short As[256 * 64];   // [row][8 chunks of 8 elems], 32 KB
    __shared__ unsigned short Bs[128 * 64];   // 16 KB

    // XCD swizzle: 8 n-tiles of one m-tile share bid&7 -> same XCD L2.
    const int bid = blockIdx.x;          // 512 blocks
    const int xcd = bid & 7;
    const int nt  = (bid >> 3) & 7;      // 8 n-tiles (128 cols each)
    const int mt  = (xcd << 3) | (bid >> 6);   // 64 m-tiles (256 rows each)
    const int m0 = mt * 256, n0 = nt * 128;

    const int t = threadIdx.x;
    const int w = t >> 6, lane = t & 63;
    const int wm = (w & 1) << 7;         // 0,128
    const int wn = (w >> 1) << 6;        // 0,64

    floatx16 acc[4][2];
#pragma unroll
    for (int i = 0; i < 4; i++)
#pragma unroll
        for (int j = 0; j < 2; j++) acc[i][j] = (floatx16)0.0f;

    // staging: wave covers 8 rows x 64 elems per gld16; source column is
    // XOR-swizzled so LDS slot (lane&7) holds global chunk (lane&7)^srow.
    const int srow = lane >> 3;                      // 0..7 (== row&7)
    const int scol = ((lane & 7) ^ srow) * 8;        // swizzled k-chunk
    // fragment addressing (32x32x16): A[m = lane&31][k = (lane>>5)*8 ..+8]
    const int fm = lane & 31;
    const int fhi = lane >> 5;                       // 0/1
    const int fsw = fm & 7;                          // row&7 for swizzle

    for (int k0 = 0; k0 < HID; k0 += 64) {
        __syncthreads();
#pragma unroll
        for (int p = 0; p < 8; p++)
            gld16(&Xb[(size_t)(m0 + p * 32 + w * 8 + srow) * HID + k0 + scol],
                  &As[(p * 32 + w * 8) * 64]);
#pragma unroll
        for (int p = 0; p < 4; p++)
            gld16(&Bt[(size_t)(n0 + p * 32 + w * 8 + srow) * HID + k0 + scol],
                  &Bs[(p * 32 + w * 8) * 64]);
        __syncthreads();

#pragma nounroll
        for (int s = 0; s < 4; s++) {            // 4 k-steps of 16
            const int ch = ((2 * s + fhi) ^ fsw) * 8;   // un-swizzled chunk
            short8 a[4], bb[2];
#pragma unroll
            for (int i = 0; i < 4; i++)
                a[i] = *(const short8*)&As[(wm + 32 * i + fm) * 64 + ch];
#pragma unroll
            for (int j = 0; j < 2; j++)
                bb[j] = *(const short8*)&Bs[(wn + 32 * j + fm) * 64 + ch];
#pragma unroll
            for (int i = 0; i < 4; i++)
#pragma unroll
                for (int j = 0; j < 2; j++)
                    acc[i][j] = __builtin_amdgcn_mfma_f32_32x32x16_bf16(
                        a[i], bb[j], acc[i][j], 0, 0, 0);
        }
    }

    // epilogue. 32x32 C/D layout: col = lane&31, row = (r&3)+8*(r>>2)+4*(lane>>5)
    const int cl = lane & 31;
    const int rhi = (lane >> 5) * 4;
    if (n0 >= 512) {
#pragma unroll
        for (int i = 0; i < 4; i++)
#pragma unroll
            for (int j = 0; j < 2; j++) {
                const int c = n0 - 512 + wn + 32 * j + cl;   // dv 0..511
#pragma unroll
                for (int r = 0; r < 16; r++) {
                    const int m = m0 + wm + 32 * i + (r & 3) + 8 * (r >> 2) + rhi;
                    Vt[(size_t)c * MROWS + m] = bf16_rne(acc[i][j][r]);
                }
            }
    } else {
        const bool isQ = (n0 < 256);
        unsigned short* dst = isQ ? Qb : Kb;
        const float sgn = isQ ? 1.f : -1.f;     // K downscaled
        const int nb = isQ ? n0 : n0 - 256;
#pragma unroll
        for (int j = 0; j < 2; j++) {
            const int c = nb + wn + 32 * j + cl;
            const float jj = (float)(c >> 1);
            const float sv = (2.f * jj + 0.4f * 256.f) * (1.f / (1.4f * 256.f));
            const float l2sv = __log2f(sv) * sgn * (1.f / 512.f);
            const float invf = exp2f(jj * (-LOG2_10000 / 128.f));
            const bool odd = (c & 1) != 0;
#pragma unroll
            for (int i = 0; i < 4; i++) {
#pragma unroll
                for (int r = 0; r < 16; r++) {
                    const int m = m0 + wm + 32 * i + (r & 3) + 8 * (r >> 2) + rhi;
                    const float s = (float)(m & (SEQ - 1));
                    const float x = acc[i][j][r];
                    const float p = __shfl_xor(x, 1, 64);   // partner col c^1
                    const float sc = exp2f(s * l2sv);
                    const float ang = s * invf;
                    const float sn = __sinf(ang), cs = __cosf(ang);
                    const float o = odd ? sc * (x * cs + p * sn)
                                        : sc * (x * cs - p * sn);
                    const unsigned short hv = bf16_rne(o);
                    dst[(size_t)m * DH + c] = hv;
                    if (!isQ) Kt[(size_t)c * MROWS + m] = hv;
                }
            }
        }
    }
}

// ---------------------------------------------------------------------------
// Kernel 2: per-chunk U_c^T = V^T diag(gamma^(C-i)) K, via bf16 MFMA.
// C[m=dv][n=dh] = sum_i Vt[dv][i] * (gamma^(C-i) Kt[dh][i]).
// Output Ut[b][c][dv 512][dh 256] fp32. Block = 128(dv) x 128(dh), K=128,
// 512 threads / 8 waves, wave 64x32. Grid = 4*32*4*2 = 1024.
// ---------------------------------------------------------------------------
__global__ __launch_bounds__(512, 1) void chunk_kv_kernel(
    const unsigned short* __restrict__ Kt, const unsigned short* __restrict__ Vt,
    float* __restrict__ Ut)
{
    __shared__ unsigned short As[128 * 32];   // Vt rows (dv) x i
    __shared__ unsigned short Bs[128 * 32];   // scaled Kt rows (dh) x i

    const int bid = blockIdx.x;      // 1024
    const int dht = bid & 1;
    const int vq  = (bid >> 1) & 3;
    const int c   = (bid >> 3) & 31;
    const int b   = bid >> 8;
    const int dh0 = dht * 128, dv0 = vq * 128;
    const int row0 = b * SEQ + c * CHUNK;

    const int t = threadIdx.x;
    const int w = t >> 6, lane = t & 63;
    const int wm = (w & 1) << 6;         // dv offset
    const int wn = (w >> 1) << 5;        // dh offset
    const int srow = lane >> 2, scol = (lane & 3) * 8;
    const int fr = lane & 15, fq = (lane >> 4) * 8;

    floatx4 acc[4][2];
#pragma unroll
    for (int i = 0; i < 4; i++)
#pragma unroll
        for (int j = 0; j < 2; j++) acc[i][j] = (floatx4)0.0f;

    const int kr = t >> 2, kc = (t & 3) * 8;   // B staging: 128 rows x 32 cols

    for (int i0 = 0; i0 < CHUNK; i0 += 32) {
        __syncthreads();
        gld16(&Vt[(size_t)(dv0 + w * 16 + srow) * MROWS + row0 + i0 + scol],
              &As[(w * 16) * 32]);
        {
            const unsigned short* src = &Kt[(size_t)(dh0 + kr) * MROWS + row0 + i0 + kc];
            ushort4 k0v = *(const ushort4*)src;
            ushort4 k1v = *(const ushort4*)(src + 4);
            float g = exp2f((float)(CHUNK - i0 - kc) * LOG2_GAMMA);  // gamma^(C-i)
            ushort4 h0, h1;
            h0.x = bf16_rne(b2f(k0v.x) * g); g *= GAMMA_INV;
            h0.y = bf16_rne(b2f(k0v.y) * g); g *= GAMMA_INV;
            h0.z = bf16_rne(b2f(k0v.z) * g); g *= GAMMA_INV;
            h0.w = bf16_rne(b2f(k0v.w) * g); g *= GAMMA_INV;
            h1.x = bf16_rne(b2f(k1v.x) * g); g *= GAMMA_INV;
            h1.y = bf16_rne(b2f(k1v.y) * g); g *= GAMMA_INV;
            h1.z = bf16_rne(b2f(k1v.z) * g); g *= GAMMA_INV;
            h1.w = bf16_rne(b2f(k1v.w) * g);
            *(ushort4*)&Bs[kr * 32 + kc] = h0;
            *(ushort4*)&Bs[kr * 32 + kc + 4] = h1;
        }
        __syncthreads();
        short8 a[4], bb[2];
#pragma unroll
        for (int i = 0; i < 4; i++)
            a[i] = *(const short8*)&As[(wm + i * 16 + fr) * 32 + fq];
#pragma unroll
        for (int j = 0; j < 2; j++)
            bb[j] = *(const short8*)&Bs[(wn + j * 16 + fr) * 32 + fq];
#pragma unroll
        for (int i = 0; i < 4; i++)
#pragma unroll
            for (int j = 0; j < 2; j++)
                acc[i][j] = __builtin_amdgcn_mfma_f32_16x16x32_bf16(a[i], bb[j], acc[i][j], 0, 0, 0);
    }

    // store: C[m=dv][n=dh] -> Ut[((b*32+c)*512 + dv0+m)*256 + dh0+n]
    const int cl = lane & 15, rq = (lane >> 4) << 2;
    const size_t ubase = ((size_t)(b * NCH + c) * DV + dv0) * DH + dh0;
#pragma unroll
    for (int i = 0; i < 4; i++)
#pragma unroll
        for (int j = 0; j < 2; j++) {
            const int n = wn + j * 16 + cl;
#pragma unroll
            for (int r = 0; r < 4; r++) {
                const int m = wm + i * 16 + rq + r;
                Ut[ubase + (size_t)m * DH + n] = acc[i][j][r];
            }
        }
}

// ---------------------------------------------------------------------------
// Kernel 3: exclusive scan over chunks; emits bf16 state Sb[c] = S_c
// (state BEFORE chunk c), layout [b][c][dv][dh] (B-operand-ready).
// ---------------------------------------------------------------------------
__global__ __launch_bounds__(256) void scan_kernel(
    const float* __restrict__ Ut, unsigned short* __restrict__ Sb)
{
    const int t = blockIdx.x * 256 + threadIdx.x;   // 0..524287
    const int b = t >> 17;                          // DV*DH = 131072
    const int r = t & 131071;
    const float gC = exp2f((float)CHUNK * LOG2_GAMMA);
    float s = 0.f;
    const size_t base = (size_t)b * NCH * 131072 + r;
    for (int c = 0; c < NCH; c++) {
        const size_t off = base + (size_t)c * 131072;
        const float u = Ut[off];
        Sb[off] = bf16_rne(s);
        s = gC * s + u;
    }
}

// ---------------------------------------------------------------------------
// Kernel 4: O = (tril(QK^T) .* gamma^(i-j)) @ V  +  (gamma^i Q) @ S_c^T.
// Full bf16 MFMA, 512 threads = 8 waves, wave 64x32. BK=64 in phases 1/3.
// Block = (b, chunk, dv-quarter): 128(i) x 128(dv) output. Grid = 512.
// ---------------------------------------------------------------------------
__global__ __launch_bounds__(512, 1) void out_mfma_kernel(
    const unsigned short* __restrict__ Qb, const unsigned short* __restrict__ Kb,
    const unsigned short* __restrict__ Vt, const unsigned short* __restrict__ Sb,
    float* __restrict__ out)
{
    __shared__ unsigned short Pa[128 * 136];   // P bf16, row stride 136 (pad)
    __shared__ unsigned short As[2 * 128 * 32];
    __shared__ unsigned short Bs[2 * 128 * 32];

    const int bid = blockIdx.x;      // 512
    const int vq = bid & 3;
    const int c  = (bid >> 2) & 31;
    const int b  = bid >> 7;
    const int dv0 = vq * 128;
    const int row0 = b * SEQ + c * CHUNK;

    const int t = threadIdx.x;
    const int w = t >> 6, lane = t & 63;
    const int wm = (w & 1) << 6;         // 0,64
    const int wn = (w >> 1) << 5;        // 0,32,64,96
    const int fr = lane & 15, fq = (lane >> 4) * 8;
    const int cl = lane & 15, rq = (lane >> 4) << 2;
    const int srow = lane >> 2, scol = (lane & 3) * 8;

    floatx4 acc[4][2];
#pragma unroll
    for (int i = 0; i < 4; i++)
#pragma unroll
        for (int j = 0; j < 2; j++) acc[i][j] = (floatx4)0.0f;

    // ---------------- phase 1: P = Q K^T (BK=64) ----------------
    for (int d0 = 0; d0 < DH; d0 += 64) {
        __syncthreads();
        gld16(&Qb[(size_t)(row0 + w * 16 + srow) * DH + d0 + scol], &As[(w * 16) * 32]);
        gld16(&Qb[(size_t)(row0 + w * 16 + srow) * DH + d0 + 32 + scol], &As[4096 + (w * 16) * 32]);
        gld16(&Kb[(size_t)(row0 + w * 16 + srow) * DH + d0 + scol], &Bs[(w * 16) * 32]);
        gld16(&Kb[(size_t)(row0 + w * 16 + srow) * DH + d0 + 32 + scol], &Bs[4096 + (w * 16) * 32]);
        __syncthreads();
#pragma nounroll
        for (int s = 0; s < 2; s++) {
            short8 a[4], bb[2];
#pragma unroll
            for (int i = 0; i < 4; i++)
                a[i] = *(const short8*)&As[s * 4096 + (wm + i * 16 + fr) * 32 + fq];
#pragma unroll
            for (int j = 0; j < 2; j++)
                bb[j] = *(const short8*)&Bs[s * 4096 + (wn + j * 16 + fr) * 32 + fq];
#pragma unroll
            for (int i = 0; i < 4; i++)
#pragma unroll
                for (int j = 0; j < 2; j++)
                    acc[i][j] = __builtin_amdgcn_mfma_f32_16x16x32_bf16(a[i], bb[j], acc[i][j], 0, 0, 0);
        }
    }

    // decay mask + bf16 -> Pa[i][j] (i = q row in chunk, j = k row)
#pragma unroll
    for (int i = 0; i < 4; i++)
#pragma unroll
        for (int j = 0; j < 2; j++) {
            const int jj = wn + j * 16 + cl;
#pragma unroll
            for (int r = 0; r < 4; r++) {
                const int ii = wm + i * 16 + rq + r;
                const int diff = ii - jj;
                const float v = (diff >= 0) ? acc[i][j][r] * exp2f((float)diff * LOG2_GAMMA) : 0.f;
                Pa[ii * 136 + jj] = bf16_rne(v);
            }
            acc[i][j] = (floatx4)0.0f;     // reset for O accumulation
        }

    // ---------------- phase 2: acc = P @ V (BK=64, K=128 total) ----------
    for (int k0 = 0; k0 < CHUNK; k0 += 64) {
        __syncthreads();   // first iter: Pa visible; later: Bs reads done
        gld16(&Vt[(size_t)(dv0 + w * 16 + srow) * MROWS + row0 + k0 + scol], &Bs[(w * 16) * 32]);
        gld16(&Vt[(size_t)(dv0 + w * 16 + srow) * MROWS + row0 + k0 + 32 + scol], &Bs[4096 + (w * 16) * 32]);
        __syncthreads();
#pragma nounroll
        for (int s = 0; s < 2; s++) {
            short8 a[4], bb[2];
#pragma unroll
            for (int i = 0; i < 4; i++)
                a[i] = *(const short8*)&Pa[(wm + i * 16 + fr) * 136 + k0 + s * 32 + fq];
#pragma unroll
            for (int j = 0; j < 2; j++)
                bb[j] = *(const short8*)&Bs[s * 4096 + (wn + j * 16 + fr) * 32 + fq];
#pragma unroll
            for (int i = 0; i < 4; i++)
#pragma unroll
                for (int j = 0; j < 2; j++)
                    acc[i][j] = __builtin_amdgcn_mfma_f32_16x16x32_bf16(a[i], bb[j], acc[i][j], 0, 0, 0);
        }
    }

    // ---------------- phase 3: acc += (gamma^i Q) @ Sb (BK=64) ------------
    const size_t sbbase = ((size_t)(b * NCH + c) * DV + dv0) * DH;
    const int xr = t >> 2, xc = (t & 3) * 8;     // A staging: 128 rows x 32 cols
    const float gx = exp2f((float)xr * LOG2_GAMMA);   // gamma^i
    for (int d0 = 0; d0 < DH; d0 += 64) {
        __syncthreads();
#pragma unroll
        for (int s = 0; s < 2; s++) {
            const unsigned short* src = &Qb[(size_t)(row0 + xr) * DH + d0 + s * 32 + xc];
            ushort4 q0 = *(const ushort4*)src;
            ushort4 q1 = *(const ushort4*)(src + 4);
            ushort4 h0, h1;
            h0.x = bf16_rne(b2f(q0.x) * gx); h0.y = bf16_rne(b2f(q0.y) * gx);
            h0.z = bf16_rne(b2f(q0.z) * gx); h0.w = bf16_rne(b2f(q0.w) * gx);
            h1.x = bf16_rne(b2f(q1.x) * gx); h1.y = bf16_rne(b2f(q1.y) * gx);
            h1.z = bf16_rne(b2f(q1.z) * gx); h1.w = bf16_rne(b2f(q1.w) * gx);
            *(ushort4*)&As[s * 4096 + xr * 32 + xc] = h0;
            *(ushort4*)&As[s * 4096 + xr * 32 + xc + 4] = h1;
        }
        gld16(&Sb[sbbase + (size_t)(w * 16 + srow) * DH + d0 + scol], &Bs[(w * 16) * 32]);
        gld16(&Sb[sbbase + (size_t)(w * 16 + srow) * DH + d0 + 32 + scol], &Bs[4096 + (w * 16) * 32]);
        __syncthreads();
#pragma nounroll
        for (int s = 0; s < 2; s++) {
            short8 a[4], bb[2];
#pragma unroll
            for (int i = 0; i < 4; i++)
                a[i] = *(const short8*)&As[s * 4096 + (wm + i * 16 + fr) * 32 + fq];
#pragma unroll
            for (int j = 0; j < 2; j++)
                bb[j] = *(const short8*)&Bs[s * 4096 + (wn + j * 16 + fr) * 32 + fq];
#pragma unroll
            for (int i = 0; i < 4; i++)
#pragma unroll
                for (int j = 0; j < 2; j++)
                    acc[i][j] = __builtin_amdgcn_mfma_f32_16x16x32_bf16(a[i], bb[j], acc[i][j], 0, 0, 0);
        }
    }

    // epilogue: fp32 store
#pragma unroll
    for (int i = 0; i < 4; i++)
#pragma unroll
        for (int j = 0; j < 2; j++) {
            const int dv = dv0 + wn + j * 16 + cl;
#pragma unroll
            for (int r = 0; r < 4; r++) {
                const int m = row0 + wm + i * 16 + rq + r;
                out[(size_t)m * DV + dv] = acc[i][j][r];
            }
        }
}

// ---------------------------------------------------------------------------
extern "C" void kernel_launch(void* const* d_in, const int* in_sizes, int n_in,
                              void* d_out, int out_size, void* d_ws, size_t ws_size,
                              hipStream_t stream) {
    const float* X  = (const float*)d_in[0];
    const float* WQ = (const float*)d_in[1];
    const float* WK = (const float*)d_in[2];
    const float* WV = (const float*)d_in[3];
    float* out = (float*)d_out;

    // Workspace layout (bf16 unless noted):
    //   Qb 8.4 | Kb 8.4 | Kt 8.4 | Vt 16.8 | Sb 33.5 | Ut fp32 67.1 | Bt 4.2
    //   Xb (67.1) OVERLAPS Ut (Xb dead after qkv; Ut written after). ~147 MB.
    char* ws = (char*)d_ws;
    unsigned short* Qb = (unsigned short*)ws;
    unsigned short* Kb = Qb + (size_t)MROWS * DH;
    unsigned short* Kt = Kb + (size_t)MROWS * DH;
    unsigned short* Vt = Kt + (size_t)MROWS * DH;
    unsigned short* Sb = Vt + (size_t)MROWS * DV;
    float*          Ut = (float*)(Sb + (size_t)NB * NCH * DV * DH);
    unsigned short* Xb = (unsigned short*)Ut;       // overlap
    unsigned short* Bt = (unsigned short*)(Ut + (size_t)NB * NCH * DV * DH);

    xcvt_kernel<<<(MROWS * HID / 4) / 256, 256, 0, stream>>>(X, Xb);
    wcvt_kernel<<<512, 256, 0, stream>>>(WQ, WK, WV, Bt);
    qkv_mfma_kernel<<<512, 256, 0, stream>>>(Xb, Bt, Qb, Kb, Kt, Vt);
    chunk_kv_kernel<<<1024, 512, 0, stream>>>(Kt, Vt, Ut);
    scan_kernel<<<2048, 256, 0, stream>>>(Ut, Sb);
    out_mfma_kernel<<<512, 512, 0, stream>>>(Qb, Kb, Vt, Sb, out);
}